// Round 2
// baseline (289.987 us; speedup 1.0000x reference)
//
#include <hip/hip_runtime.h>
#include <hip/hip_bf16.h>

#define B_ 16
#define T_ 16384
#define C_ 8
#define L_ 16384
#define W_ 256
#define R_ 32

typedef __bf16 bf16x8 __attribute__((ext_vector_type(8)));
typedef float f32x4 __attribute__((ext_vector_type(4)));

// ---------------------------------------------------------------------------
// Kernel 1: x (B,T,C) fp32 -> xt (B,C,L) bf16, fully coalesced via LDS tile.
// Block = 256 threads handles (b, 256 t) for all 8 c.
// ---------------------------------------------------------------------------
__global__ void xconv_kernel(const float* __restrict__ x,
                             unsigned short* __restrict__ xt) {
  __shared__ unsigned short Xl[8][264];
  const int tid = threadIdx.x;
  const int b = blockIdx.x >> 6;
  const int t0 = (blockIdx.x & 63) << 8;
  const float4* src = reinterpret_cast<const float4*>(x + ((size_t)b * T_ + t0) * C_);
  #pragma unroll
  for (int h = 0; h < 2; ++h) {
    const int vi = h * 256 + tid;          // float4 index within 2048-float tile
    float4 v = src[vi];
    const int e = vi * 4;                  // element index: c = e&7, tt = e>>3
    const int tt = e >> 3;
    const int c0 = e & 7;                  // 0 or 4
    Xl[c0 + 0][tt] = __builtin_bit_cast(unsigned short, (__bf16)v.x);
    Xl[c0 + 1][tt] = __builtin_bit_cast(unsigned short, (__bf16)v.y);
    Xl[c0 + 2][tt] = __builtin_bit_cast(unsigned short, (__bf16)v.z);
    Xl[c0 + 3][tt] = __builtin_bit_cast(unsigned short, (__bf16)v.w);
  }
  __syncthreads();
  const int c = tid >> 5;
  const int toff = (tid & 31) * 8;
  const unsigned short* p = &Xl[c][toff];
  uint4 o;
  o.x = (unsigned)p[0] | ((unsigned)p[1] << 16);
  o.y = (unsigned)p[2] | ((unsigned)p[3] << 16);
  o.z = (unsigned)p[4] | ((unsigned)p[5] << 16);
  o.w = (unsigned)p[6] | ((unsigned)p[7] << 16);
  *reinterpret_cast<uint4*>(xt + ((size_t)b * C_ + c) * L_ + t0 + toff) = o;
}

// ---------------------------------------------------------------------------
// Kernel 2: Gabor bank -> Fg[c][j][w] bf16; j<32 real(r=j), j>=32 imag;
// param index = c*32 + (31 - r)  (bakes the [::-1])
// ---------------------------------------------------------------------------
__global__ void gen_filters_kernel(const float* __restrict__ kv,
                                   const float* __restrict__ sv,
                                   unsigned short* __restrict__ Fg) {
  unsigned idx = blockIdx.x * 256u + threadIdx.x;   // [0, 8*64*256)
  unsigned w = idx & (W_ - 1);
  unsigned j = (idx >> 8) & 63u;
  unsigned c = idx >> 14;
  unsigned r = j & 31u;
  unsigned pidx = c * 32u + (31u - r);
  float k  = kv[pidx];
  float sg = sv[pidx];
  float phase = (-6.283185307179586f / (float)W_) * k * (float)w;
  float dn = (float)w - (float)(W_ / 2);
  float var2 = 2.0f * sg * sg;
  float g = (1.0f / sqrtf(3.14159265358979f * var2)) * expf(-(dn * dn) / var2);
  float s, cth;
  sincosf(phase, &s, &cth);
  float v = (j < 32u) ? cth * g : s * g;
  Fg[idx] = __builtin_bit_cast(unsigned short, (__bf16)v);
}

// ---------------------------------------------------------------------------
// Kernel 3: persistent-block MFMA kernel.
// Grid = 512 blocks (16 b x 8 c x 4 parts), 256 threads = 4 waves.
// Each block loops 16 t-tiles of 256 rows. Filters staged once (33.8 KB).
// X staged as a full sliding-window table: chunk s (byte offset 16s) holds
// xwin[s..s+7], so every A fragment is ONE aligned ds_read_b128.
// Double-buffered (2 x 8 KB), one barrier per iteration.
// ---------------------------------------------------------------------------
__global__ __launch_bounds__(256, 2) void wavelet_main_kernel(
    const unsigned short* __restrict__ xt,   // [B][C][L] bf16
    const unsigned short* __restrict__ Fg,   // [C][64][256] bf16
    float* __restrict__ out)                 // [B][L][256] fp32
{
  __shared__ __align__(16) unsigned int Fs[64 * 132];   // 33792 B, row pad +8 bf16
  __shared__ __align__(16) unsigned int Xs[2][2048];    // 2 x 8192 B window tables

  const int tid = threadIdx.x;
  const unsigned bid = blockIdx.x;
  const int p = bid & 3;
  const int c = (bid >> 2) & 7;
  const int b = bid >> 5;
  const unsigned short* __restrict__ xrow = xt + ((size_t)b * C_ + c) * L_;

  // ---- stage filters once: 64x256 bf16 = 2048 uint4 ----
  {
    const uint4* Fg4 = reinterpret_cast<const uint4*>(Fg + (size_t)c * (64 * 256));
    #pragma unroll
    for (int i8 = 0; i8 < 8; ++i8) {
      int i = i8 * 256 + tid;
      uint4 v = Fg4[i];
      *reinterpret_cast<uint4*>(&Fs[(i >> 5) * 132 + ((i & 31) << 2)]) = v;
    }
  }

  const int s0 = 2 * tid;                  // this thread's two chunks: s0, s0+1

  // Load the 32B of x feeding chunks s0,s0+1 of window starting at t0.
  auto load_window = [&](int t0, uint4& v0, uint4& v1) {
    const int gbase = t0 - 128 + (s0 & ~7);     // 8-elt aligned -> 16B aligned
    if (t0 >= 128 && t0 + 392 <= L_) {
      const uint4* g = reinterpret_cast<const uint4*>(xrow + gbase);
      v0 = g[0];
      v1 = g[1];
    } else {
      unsigned int d[8];
      #pragma unroll
      for (int q = 0; q < 8; ++q) {
        int g0 = gbase + 2 * q, g1 = g0 + 1;
        unsigned lo = (g0 >= 0 && g0 < L_) ? (unsigned)xrow[g0] : 0u;
        unsigned hi = (g1 >= 0 && g1 < L_) ? (unsigned)xrow[g1] : 0u;
        d[q] = lo | (hi << 16);
      }
      v0 = make_uint4(d[0], d[1], d[2], d[3]);
      v1 = make_uint4(d[4], d[5], d[6], d[7]);
    }
  };

  // Build chunks s0 (shift 2*(tid&3) dwords) and s0+1 (+2 bytes), write LDS.
  auto write_window = [&](int buf, const uint4& v0, const uint4& v1) {
    const bool a2 = (tid & 2) != 0;
    unsigned u0 = a2 ? v0.z : v0.x;
    unsigned u1 = a2 ? v0.w : v0.y;
    unsigned u2 = a2 ? v1.x : v0.z;
    unsigned u3 = a2 ? v1.y : v0.w;
    unsigned u4 = a2 ? v1.z : v1.x;
    unsigned u5 = a2 ? v1.w : v1.y;
    const bool a1 = (tid & 1) != 0;
    unsigned e0 = a1 ? u1 : u0;
    unsigned e1 = a1 ? u2 : u1;
    unsigned e2 = a1 ? u3 : u2;
    unsigned e3 = a1 ? u4 : u3;
    unsigned e4 = a1 ? u5 : u4;
    uint4 c0 = make_uint4(e0, e1, e2, e3);
    uint4 c1 = make_uint4((e0 >> 16) | (e1 << 16),
                          (e1 >> 16) | (e2 << 16),
                          (e2 >> 16) | (e3 << 16),
                          (e3 >> 16) | (e4 << 16));
    *reinterpret_cast<uint4*>(&Xs[buf][s0 * 4]) = c0;
    *reinterpret_cast<uint4*>(&Xs[buf][s0 * 4 + 4]) = c1;
  };

  const int lane = tid & 63;
  const int wv   = tid >> 6;
  const int quad = lane >> 4;
  const int lrow = lane & 15;
  const size_t obase = ((size_t)b * L_) * 256 + (size_t)c * 32 + lrow;

  auto compute = [&](int buf, int t0) {
    f32x4 acc[4][4];
    #pragma unroll
    for (int mt = 0; mt < 4; ++mt)
      #pragma unroll
      for (int nt = 0; nt < 4; ++nt)
        acc[mt][nt] = (f32x4){0.f, 0.f, 0.f, 0.f};

    #pragma unroll
    for (int kk = 0; kk < 8; ++kk) {
      bf16x8 bfr[4], afr[4];
      #pragma unroll
      for (int nt = 0; nt < 4; ++nt)
        bfr[nt] = __builtin_bit_cast(bf16x8, *reinterpret_cast<const uint4*>(
            &Fs[(nt * 16 + lrow) * 132 + kk * 16 + quad * 4]));
      #pragma unroll
      for (int mt = 0; mt < 4; ++mt) {
        const int s = wv * 64 + mt * 16 + lrow + kk * 32 + quad * 8;
        afr[mt] = __builtin_bit_cast(bf16x8, *reinterpret_cast<const uint4*>(
            &Xs[buf][s * 4]));
      }
      #pragma unroll
      for (int mt = 0; mt < 4; ++mt)
        #pragma unroll
        for (int nt = 0; nt < 4; ++nt)
          acc[mt][nt] = __builtin_amdgcn_mfma_f32_16x16x32_bf16(
              afr[mt], bfr[nt], acc[mt][nt], 0, 0, 0);
    }

    // power = real^2 + imag^2 ; D layout: row = quad*4+i, col = lane&15
    #pragma unroll
    for (int mt = 0; mt < 4; ++mt)
      #pragma unroll
      for (int i = 0; i < 4; ++i) {
        const int t = t0 + wv * 64 + mt * 16 + quad * 4 + i;
        float* orow = out + obase + (size_t)t * 256;
        orow[0]  = acc[mt][0][i] * acc[mt][0][i] + acc[mt][2][i] * acc[mt][2][i];
        orow[16] = acc[mt][1][i] * acc[mt][1][i] + acc[mt][3][i] * acc[mt][3][i];
      }
  };

  const int tstart = p * 4096;
  {
    uint4 v0, v1;
    load_window(tstart, v0, v1);
    write_window(0, v0, v1);
  }
  __syncthreads();

  #pragma unroll 1
  for (int it = 0; it < 16; ++it) {
    const int t0 = tstart + it * 256;
    uint4 v0, v1;
    if (it < 15) load_window(t0 + 256, v0, v1);   // prefetch next (regs)
    compute(it & 1, t0);
    if (it < 15) write_window((it + 1) & 1, v0, v1);
    __syncthreads();
  }
}

// ---------------------------------------------------------------------------
extern "C" void kernel_launch(void* const* d_in, const int* in_sizes, int n_in,
                              void* d_out, int out_size, void* d_ws, size_t ws_size,
                              hipStream_t stream) {
  const float* x  = (const float*)d_in[0];
  const float* kv = (const float*)d_in[1];
  const float* sv = (const float*)d_in[2];
  float* out = (float*)d_out;

  unsigned short* xt = (unsigned short*)d_ws;                 // B*C*L bf16 = 4 MB
  unsigned short* Fg = xt + (size_t)B_ * C_ * L_;             // 8*64*256 bf16 = 256 KB

  hipLaunchKernelGGL(xconv_kernel, dim3(B_ * (L_ / 256)), dim3(256), 0, stream,
                     x, xt);
  hipLaunchKernelGGL(gen_filters_kernel, dim3((C_ * 64 * W_) / 256), dim3(256), 0, stream,
                     kv, sv, Fg);
  hipLaunchKernelGGL(wavelet_main_kernel, dim3(512), dim3(256), 0, stream,
                     xt, Fg, out);
}